// Round 1
// baseline (446.051 us; speedup 1.0000x reference)
//
#include <hip/hip_runtime.h>
#include <math.h>

#define C   5
#define NPC 400
#define DF  64
#define HH  256
#define DOUT 64
#define EPC 12800
#define NN  (C*NPC)   // 2000

// ---------------- K1: degree + 1/sqrt(deg) per cluster ----------------
__global__ void deg_kernel(const float* __restrict__ ew, const int* __restrict__ ei,
                           float* __restrict__ dis) {
    __shared__ float sdeg[NPC];
    int c = blockIdx.x;
    int tid = threadIdx.x;
    for (int n = tid; n < NPC; n += blockDim.x) sdeg[n] = 1.0f;  // self-loop weight
    __syncthreads();
    const int* col = ei + (size_t)c*2*EPC + EPC;
    const float* w = ew + (size_t)c*EPC;
    for (int e = tid; e < EPC; e += blockDim.x)
        atomicAdd(&sdeg[col[e]], w[e]);
    __syncthreads();
    for (int n = tid; n < NPC; n += blockDim.x) {
        float d = sdeg[n];
        dis[c*NPC + n] = (d > 0.f) ? 1.0f/sqrtf(d) : 0.f;
    }
}

// ---------------- K2: build dense normalized adjacency A[col][row] ----------------
__global__ void build_adj(const float* __restrict__ ew, const int* __restrict__ ei,
                          const float* __restrict__ dis, float* __restrict__ Amat) {
    int c = blockIdx.x;
    int tid = threadIdx.x;
    const int* row = ei + (size_t)c*2*EPC;
    const int* col = row + EPC;
    const float* w = ew + (size_t)c*EPC;
    const float* dc = dis + c*NPC;
    float* A = Amat + (size_t)c*NPC*NPC;
    for (int e = tid; e < EPC; e += blockDim.x) {
        int r = row[e], cc = col[e];
        atomicAdd(&A[(size_t)cc*NPC + r], dc[r]*w[e]*dc[cc]);
    }
    // self loops: norm = dis[n]*1*dis[n]
    for (int n = tid; n < NPC; n += blockDim.x)
        atomicAdd(&A[(size_t)n*NPC + n], dc[n]*dc[n]);
}

// ---------------- generic small dense GEMM: out[c] = opt(A[c]@B[c] + bias[c]) ----------------
template<int BIAS, int RELU>
__global__ void gemm(const float* __restrict__ A, const float* __restrict__ B,
                     const float* __restrict__ bias, float* __restrict__ out,
                     int M, int K, int N2) {
    int c = blockIdx.y;
    int idx = blockIdx.x*blockDim.x + threadIdx.x;
    if (idx >= M*N2) return;
    int m = idx / N2, n = idx % N2;
    const float* Ar = A + (size_t)c*M*K + (size_t)m*K;
    const float* Bc = B + (size_t)c*K*N2 + n;
    float acc = 0.f;
    for (int k = 0; k < K; ++k) acc += Ar[k]*Bc[(size_t)k*N2];
    if (BIAS) acc += bias[c*N2 + n];
    if (RELU) acc = fmaxf(acc, 0.f);
    out[(size_t)c*M*N2 + idx] = acc;
}

// ---------------- K7: a[n] = feat[n]·Wa, b[n] = feat[n]·Wb ----------------
__global__ void attvec(const float* __restrict__ h2, const float* __restrict__ Watt,
                       float* __restrict__ av, float* __restrict__ bv) {
    int n = blockIdx.x*blockDim.x + threadIdx.x;
    if (n >= NN) return;
    const float* f = h2 + (size_t)n*DOUT;
    float a = 0.f, b = 0.f;
    for (int d = 0; d < DOUT; ++d) {
        a += f[d]*Watt[d];
        b += f[d]*Watt[DOUT + d];
    }
    av[n] = a; bv[n] = b;
}

// ---------------- K8: closed-form mean/std over all P pairs (double precision) ----------------
__global__ void stats_kernel(const float* __restrict__ av, const float* __restrict__ bv,
                             const float* __restrict__ b_att, float* __restrict__ stats) {
    __shared__ double sh[256];
    __shared__ double pref[256];
    __shared__ double tot[5];
    int t = threadIdx.x;
    const int CH = 8;                // 256*8 = 2048 >= 2000
    int lo = t*CH, hi = lo+CH; if (hi > NN) hi = NN; if (lo > NN) lo = NN;

    double sa1=0, sb1=0, sa2=0, sb2=0, csum=0;
    for (int i = lo; i < hi; ++i) {
        double a = av[i], b = bv[i];
        double wa = (double)(NN-1-i), wb = (double)i;
        sa1 += a*wa; sb1 += b*wb;
        sa2 += a*a*wa; sb2 += b*b*wb;
        csum += a;
    }
    double vals[4] = {sa1, sb1, sa2, sb2};
    for (int v = 0; v < 4; ++v) {
        sh[t] = vals[v]; __syncthreads();
        if (t == 0) { double s = 0; for (int i = 0; i < 256; ++i) s += sh[i]; tot[v] = s; }
        __syncthreads();
    }
    // exclusive prefix of per-chunk sums of a
    sh[t] = csum; __syncthreads();
    if (t == 0) { double run = 0; for (int i = 0; i < 256; ++i) { pref[i] = run; run += sh[i]; } }
    __syncthreads();
    // cross term CT = sum_{i<j} a_i b_j
    double run = pref[t], ct = 0;
    for (int i = lo; i < hi; ++i) { ct += (double)bv[i]*run; run += (double)av[i]; }
    __syncthreads();
    sh[t] = ct; __syncthreads();
    if (t == 0) {
        double CT = 0; for (int i = 0; i < 256; ++i) CT += sh[i];
        double cc = (double)b_att[0];
        double P  = (double)NN*(double)(NN-1)/2.0;
        double S1 = tot[0] + tot[1] + cc*P;
        double S2 = tot[2] + tot[3] + 2.0*CT + 2.0*cc*S1 - cc*cc*P;
        double m  = S1/P;
        double var = (S2 - S1*S1/P)/(P - 1.0);
        stats[0] = (float)m;
        stats[1] = (float)sqrt(var);
    }
}

// ---------------- K9: all-pairs sigmoid output, one block per row i ----------------
__global__ void pair_kernel(const float* __restrict__ av, const float* __restrict__ bv,
                            const float* __restrict__ b_att, const float* __restrict__ stats,
                            float* __restrict__ out) {
    int i = blockIdx.x;
    long off = (long)i*(NN-1) - ((long)i*(i-1))/2;
    float m = stats[0], s = stats[1];
    float inv = 1.0f/s;
    float ai = av[i] + b_att[0] - m;
    for (int j = i + 1 + threadIdx.x; j < NN; j += blockDim.x) {
        float z = (ai + bv[j]) * inv;
        out[off + (j - i - 1)] = 1.0f/(1.0f + __expf(-z));
    }
}

extern "C" void kernel_launch(void* const* d_in, const int* in_sizes, int n_in,
                              void* d_out, int out_size, void* d_ws, size_t ws_size,
                              hipStream_t stream) {
    const float* x    = (const float*)d_in[0];
    const float* ew   = (const float*)d_in[1];
    const float* W1   = (const float*)d_in[2];
    const float* b1   = (const float*)d_in[3];
    const float* W2   = (const float*)d_in[4];
    const float* b2   = (const float*)d_in[5];
    const float* Watt = (const float*)d_in[6];
    const float* batt = (const float*)d_in[7];
    const int*   ei   = (const int*)d_in[8];
    float* out = (float*)d_out;
    float* ws  = (float*)d_ws;

    // workspace layout (floats)
    float* dis   = ws;                 // C*NPC            = 2000
    float* Amat  = dis  + 2000;        // C*NPC*NPC        = 800000
    float* xW    = Amat + 800000;      // C*NPC*HH         = 512000
    float* h1    = xW   + 512000;      // C*NPC*HH         = 512000
    float* hW2   = h1   + 512000;      // C*NPC*DOUT       = 128000
    float* h2    = hW2  + 128000;      // C*NPC*DOUT       = 128000
    float* av    = h2   + 128000;      // NN               = 2000
    float* bv    = av   + 2000;        // NN               = 2000
    float* stats = bv   + 2000;        // 2

    hipMemsetAsync(Amat, 0, (size_t)C*NPC*NPC*sizeof(float), stream);

    deg_kernel<<<C, 256, 0, stream>>>(ew, ei, dis);
    build_adj<<<C, 256, 0, stream>>>(ew, ei, dis, Amat);

    // layer 1: xW = x@W1 ; h1 = relu(A@xW + b1)
    gemm<0,0><<<dim3((NPC*HH+255)/256, C), 256, 0, stream>>>(x,    W1, nullptr, xW, NPC, DF,  HH);
    gemm<1,1><<<dim3((NPC*HH+255)/256, C), 256, 0, stream>>>(Amat, xW, b1,      h1, NPC, NPC, HH);
    // layer 2: hW2 = h1@W2 ; h2 = A@hW2 + b2
    gemm<0,0><<<dim3((NPC*DOUT+255)/256, C), 256, 0, stream>>>(h1,   W2,  nullptr, hW2, NPC, HH,  DOUT);
    gemm<1,0><<<dim3((NPC*DOUT+255)/256, C), 256, 0, stream>>>(Amat, hW2, b2,      h2,  NPC, NPC, DOUT);

    attvec<<<(NN+255)/256, 256, 0, stream>>>(h2, Watt, av, bv);
    stats_kernel<<<1, 256, 0, stream>>>(av, bv, batt, stats);
    pair_kernel<<<NN, 256, 0, stream>>>(av, bv, batt, stats, out);
}

// Round 2
// 199.900 us; speedup vs baseline: 2.2314x; 2.2314x over previous
//
#include <hip/hip_runtime.h>
#include <math.h>

#define C    5
#define NPC  400
#define DF   64
#define HH   256
#define DOUT 64
#define EPC  12800
#define NN   (C*NPC)   // 2000

// ---------------- K1: degree + dis + dense normalized adjacency (fused) ----------------
// A[c][col][row] = dis[row]*w*dis[col]  (so out[col] = sum_row A[col][row]*h[row])
__global__ void build_kernel(const float* __restrict__ ew, const int* __restrict__ ei,
                             float* __restrict__ Amat) {
    __shared__ float sdeg[NPC];
    __shared__ float dis[NPC];
    int c = blockIdx.x, tid = threadIdx.x;
    for (int n = tid; n < NPC; n += 256) sdeg[n] = 1.0f;   // self-loop weight
    __syncthreads();
    const int* row = ei + (size_t)c*2*EPC;
    const int* col = row + EPC;
    const float* w = ew + (size_t)c*EPC;
    for (int e = tid; e < EPC; e += 256) atomicAdd(&sdeg[col[e]], w[e]);
    __syncthreads();
    for (int n = tid; n < NPC; n += 256) {
        float d = sdeg[n];
        dis[n] = (d > 0.f) ? 1.0f/sqrtf(d) : 0.f;
    }
    __syncthreads();
    float* A = Amat + (size_t)c*NPC*NPC;
    for (int e = tid; e < EPC; e += 256) {
        int r = row[e], cc = col[e];
        atomicAdd(&A[(size_t)cc*NPC + r], dis[r]*w[e]*dis[cc]);
    }
    for (int n = tid; n < NPC; n += 256)
        atomicAdd(&A[(size_t)n*NPC + n], dis[n]*dis[n]);
}

// ---------------- tiled f32 GEMM: out[c] = opt(A[c]@B[c] + bias[c]) ----------------
// BM=BN=64, BK=16, 256 threads, 4x4 per thread. Requires K%16==0, N2%64==0.
template<int M, int K, int N2, int BIAS, int RELU>
__global__ __launch_bounds__(256) void gemm_tiled(const float* __restrict__ A,
        const float* __restrict__ B, const float* __restrict__ bias,
        float* __restrict__ out) {
    __shared__ float As[16][68];   // [kk][row], pad 68 keeps conflicts <=2-way
    __shared__ float Bs[16][68];   // [kk][col]
    const int c  = blockIdx.z;
    const int m0 = blockIdx.x << 6, n0 = blockIdx.y << 6;
    const float* Ab = A + (size_t)c*M*K;
    const float* Bb = B + (size_t)c*K*N2;
    const int tid = threadIdx.x;
    const int tx = tid & 15, ty = tid >> 4;
    const int lrow = tid >> 2, lk4 = (tid & 3) << 2;     // A loader: 64 rows x 16 k
    const int lkb = tid >> 4, lcol4 = (tid & 15) << 2;   // B loader: 16 k x 64 cols
    float acc[4][4] = {};
    for (int k0 = 0; k0 < K; k0 += 16) {
        float4 a4 = make_float4(0.f, 0.f, 0.f, 0.f);
        int gr = m0 + lrow;
        if (gr < M) a4 = *(const float4*)(Ab + (size_t)gr*K + k0 + lk4);
        As[lk4+0][lrow] = a4.x; As[lk4+1][lrow] = a4.y;
        As[lk4+2][lrow] = a4.z; As[lk4+3][lrow] = a4.w;
        *(float4*)&Bs[lkb][lcol4] = *(const float4*)(Bb + (size_t)(k0+lkb)*N2 + n0 + lcol4);
        __syncthreads();
        #pragma unroll
        for (int kk = 0; kk < 16; ++kk) {
            float4 av = *(float4*)&As[kk][ty << 2];
            float4 bv = *(float4*)&Bs[kk][tx << 2];
            acc[0][0] += av.x*bv.x; acc[0][1] += av.x*bv.y; acc[0][2] += av.x*bv.z; acc[0][3] += av.x*bv.w;
            acc[1][0] += av.y*bv.x; acc[1][1] += av.y*bv.y; acc[1][2] += av.y*bv.z; acc[1][3] += av.y*bv.w;
            acc[2][0] += av.z*bv.x; acc[2][1] += av.z*bv.y; acc[2][2] += av.z*bv.z; acc[2][3] += av.z*bv.w;
            acc[3][0] += av.w*bv.x; acc[3][1] += av.w*bv.y; acc[3][2] += av.w*bv.z; acc[3][3] += av.w*bv.w;
        }
        __syncthreads();
    }
    #pragma unroll
    for (int i = 0; i < 4; ++i) {
        int gr = m0 + (ty << 2) + i;
        if (gr >= M) break;
        float4 o = make_float4(acc[i][0], acc[i][1], acc[i][2], acc[i][3]);
        if (BIAS) {
            const float* bb = bias + c*N2 + n0 + (tx << 2);
            o.x += bb[0]; o.y += bb[1]; o.z += bb[2]; o.w += bb[3];
        }
        if (RELU) {
            o.x = fmaxf(o.x, 0.f); o.y = fmaxf(o.y, 0.f);
            o.z = fmaxf(o.z, 0.f); o.w = fmaxf(o.w, 0.f);
        }
        *(float4*)(out + (size_t)c*M*N2 + (size_t)gr*N2 + n0 + (tx << 2)) = o;
    }
}

// ---------------- wprep: wa2 = W2@Wa, wb2 = W2@Wb (per cluster), cab = b2·{Wa,Wb} ----------------
__global__ void wprep(const float* __restrict__ W2, const float* __restrict__ Watt,
                      const float* __restrict__ b2, float* __restrict__ wa2,
                      float* __restrict__ wb2, float* __restrict__ cab) {
    int t = threadIdx.x;
    for (int idx = t; idx < C*HH; idx += 256) {
        int c = idx / HH, k = idx % HH;
        const float* w2 = W2 + ((size_t)c*HH + k)*DOUT;
        float sa = 0.f, sb = 0.f;
        for (int d = 0; d < DOUT; ++d) { sa += w2[d]*Watt[d]; sb += w2[d]*Watt[DOUT+d]; }
        wa2[idx] = sa; wb2[idx] = sb;
    }
    if (t < 2*C) {
        int c = t % C, which = t / C;
        const float* bb = b2 + c*DOUT;
        const float* wv = Watt + which*DOUT;
        float s = 0.f;
        for (int d = 0; d < DOUT; ++d) s += bb[d]*wv[d];
        cab[t] = s;   // [0..4]=b2·Wa, [5..9]=b2·Wb
    }
}

// ---------------- tvec: ta[n] = h1[n]·wa2[c], tb[n] = h1[n]·wb2[c] (one wave per node) ----------------
__global__ void tvec(const float* __restrict__ h1, const float* __restrict__ wa2,
                     const float* __restrict__ wb2, float* __restrict__ ta,
                     float* __restrict__ tb) {
    int w = blockIdx.x*4 + (threadIdx.x >> 6);
    int lane = threadIdx.x & 63;
    if (w >= NN) return;
    int c = w / NPC;
    const float* hr = h1 + (size_t)w*HH;
    const float* wa = wa2 + c*HH;
    const float* wb = wb2 + c*HH;
    float sa = 0.f, sb = 0.f;
    for (int d = lane; d < HH; d += 64) { float h = hr[d]; sa += h*wa[d]; sb += h*wb[d]; }
    for (int off = 32; off; off >>= 1) { sa += __shfl_down(sa, off); sb += __shfl_down(sb, off); }
    if (!lane) { ta[w] = sa; tb[w] = sb; }
}

// ---------------- avbv: av[n] = A_row(n)·ta + b2·Wa   (one wave per node) ----------------
__global__ void avbv(const float* __restrict__ Amat, const float* __restrict__ ta,
                     const float* __restrict__ tb, const float* __restrict__ cab,
                     float* __restrict__ av, float* __restrict__ bv) {
    int w = blockIdx.x*4 + (threadIdx.x >> 6);
    int lane = threadIdx.x & 63;
    if (w >= NN) return;
    int c = w / NPC, n = w % NPC;
    const float* Ar = Amat + (size_t)c*NPC*NPC + (size_t)n*NPC;
    const float* tac = ta + c*NPC;
    const float* tbc = tb + c*NPC;
    float sa = 0.f, sb = 0.f;
    for (int m = lane; m < NPC; m += 64) { float a = Ar[m]; sa += a*tac[m]; sb += a*tbc[m]; }
    for (int off = 32; off; off >>= 1) { sa += __shfl_down(sa, off); sb += __shfl_down(sb, off); }
    if (!lane) { av[w] = sa + cab[c]; bv[w] = sb + cab[5 + c]; }
}

// ---------------- stats: closed-form mean/std over all P pairs (double precision) ----------------
__global__ void stats_kernel(const float* __restrict__ av, const float* __restrict__ bv,
                             const float* __restrict__ b_att, float* __restrict__ stats) {
    __shared__ double sh[256];
    __shared__ double pref[256];
    __shared__ double tot[5];
    int t = threadIdx.x;
    const int CH = 8;
    int lo = t*CH, hi = lo + CH; if (hi > NN) hi = NN; if (lo > NN) lo = NN;

    double sa1=0, sb1=0, sa2=0, sb2=0, csum=0;
    for (int i = lo; i < hi; ++i) {
        double a = av[i], b = bv[i];
        double wa = (double)(NN-1-i), wb = (double)i;
        sa1 += a*wa; sb1 += b*wb;
        sa2 += a*a*wa; sb2 += b*b*wb;
        csum += a;
    }
    double vals[4] = {sa1, sb1, sa2, sb2};
    for (int v = 0; v < 4; ++v) {
        sh[t] = vals[v]; __syncthreads();
        if (t == 0) { double s = 0; for (int i = 0; i < 256; ++i) s += sh[i]; tot[v] = s; }
        __syncthreads();
    }
    sh[t] = csum; __syncthreads();
    if (t == 0) { double run = 0; for (int i = 0; i < 256; ++i) { pref[i] = run; run += sh[i]; } }
    __syncthreads();
    double run = pref[t], ct = 0;
    for (int i = lo; i < hi; ++i) { ct += (double)bv[i]*run; run += (double)av[i]; }
    __syncthreads();
    sh[t] = ct; __syncthreads();
    if (t == 0) {
        double CT = 0; for (int i = 0; i < 256; ++i) CT += sh[i];
        double cc = (double)b_att[0];
        double P  = (double)NN*(double)(NN-1)/2.0;
        double S1 = tot[0] + tot[1] + cc*P;
        double S2 = tot[2] + tot[3] + 2.0*CT + 2.0*cc*S1 - cc*cc*P;
        double m  = S1/P;
        double var = (S2 - S1*S1/P)/(P - 1.0);
        stats[0] = (float)m;
        stats[1] = (float)sqrt(var);
    }
}

// ---------------- pair: all-pairs sigmoid output, one block per row i ----------------
__global__ void pair_kernel(const float* __restrict__ av, const float* __restrict__ bv,
                            const float* __restrict__ b_att, const float* __restrict__ stats,
                            float* __restrict__ out) {
    int i = blockIdx.x;
    long off = (long)i*(NN-1) - ((long)i*(i-1))/2;
    float m = stats[0], s = stats[1];
    float inv = 1.0f/s;
    float ai = av[i] + b_att[0] - m;
    for (int j = i + 1 + threadIdx.x; j < NN; j += blockDim.x) {
        float z = (ai + bv[j]) * inv;
        out[off + (j - i - 1)] = 1.0f/(1.0f + __expf(-z));
    }
}

extern "C" void kernel_launch(void* const* d_in, const int* in_sizes, int n_in,
                              void* d_out, int out_size, void* d_ws, size_t ws_size,
                              hipStream_t stream) {
    const float* x    = (const float*)d_in[0];
    const float* ew   = (const float*)d_in[1];
    const float* W1   = (const float*)d_in[2];
    const float* b1   = (const float*)d_in[3];
    const float* W2   = (const float*)d_in[4];
    const float* b2   = (const float*)d_in[5];
    const float* Watt = (const float*)d_in[6];
    const float* batt = (const float*)d_in[7];
    const int*   ei   = (const int*)d_in[8];
    float* out = (float*)d_out;
    float* ws  = (float*)d_ws;

    // workspace layout (floats)
    float* Amat  = ws;                  // 800000
    float* xW    = Amat + 800000;       // 512000
    float* h1    = xW   + 512000;       // 512000
    float* wa2   = h1   + 512000;       // 1280
    float* wb2   = wa2  + 1280;         // 1280
    float* cab   = wb2  + 1280;         // 10 (+pad 2)
    float* ta    = cab  + 12;           // 2000
    float* tb    = ta   + 2000;         // 2000
    float* av    = tb   + 2000;         // 2000
    float* bv    = av   + 2000;         // 2000
    float* stats = bv   + 2000;         // 2

    hipMemsetAsync(Amat, 0, (size_t)C*NPC*NPC*sizeof(float), stream);
    build_kernel<<<C, 256, 0, stream>>>(ew, ei, Amat);

    // layer 1: xW = x@W1 ; h1 = relu(A@xW + b1)
    gemm_tiled<NPC, DF,  HH, 0, 0><<<dim3(7, 4, C), 256, 0, stream>>>(x,    W1, nullptr, xW);
    gemm_tiled<NPC, NPC, HH, 1, 1><<<dim3(7, 4, C), 256, 0, stream>>>(Amat, xW, b1,      h1);

    // layer 2 collapsed: av = A@(h1@(W2·Wa)) + b2·Wa  (same for b)
    wprep<<<1, 256, 0, stream>>>(W2, Watt, b2, wa2, wb2, cab);
    tvec<<<(NN + 3)/4, 256, 0, stream>>>(h1, wa2, wb2, ta, tb);
    avbv<<<(NN + 3)/4, 256, 0, stream>>>(Amat, ta, tb, cab, av, bv);

    stats_kernel<<<1, 256, 0, stream>>>(av, bv, batt, stats);
    pair_kernel<<<NN, 256, 0, stream>>>(av, bv, batt, stats, out);
}

// Round 3
// 141.030 us; speedup vs baseline: 3.1628x; 1.4174x over previous
//
#include <hip/hip_runtime.h>
#include <math.h>

#define C    5
#define NPC  400
#define DF   64
#define HH   256
#define DOUT 64
#define EPC  12800
#define NN   (C*NPC)   // 2000
#define NE   (C*EPC)   // 64000

// ---------------- K1: edge-weight degree scatter (deg = edge-sum only; +1 self-loop later) ----
__global__ void deg_kernel(const float* __restrict__ ew, const int* __restrict__ ei,
                           float* __restrict__ deg) {
    int idx = blockIdx.x*256 + threadIdx.x;
    if (idx >= NE) return;
    int c = idx / EPC, e = idx % EPC;
    int col = ei[(size_t)c*2*EPC + EPC + e];
    atomicAdd(&deg[c*NPC + col], ew[(size_t)c*EPC + e]);
}

// ---------------- K2: dense normalized adjacency scatter ----------------
// A[c][col][row] = dis[row]*w*dis[col], dis = rsqrt(deg+1); diag += 1/(deg+1)
__global__ void adj_kernel(const float* __restrict__ ew, const int* __restrict__ ei,
                           const float* __restrict__ deg, float* __restrict__ Amat) {
    int idx = blockIdx.x*256 + threadIdx.x;
    if (idx < NE) {
        int c = idx / EPC, e = idx % EPC;
        const int* row = ei + (size_t)c*2*EPC;
        int r  = row[e];
        int cc = row[EPC + e];
        float w  = ew[(size_t)c*EPC + e];
        float dr = rsqrtf(deg[c*NPC + r]  + 1.0f);
        float dc = rsqrtf(deg[c*NPC + cc] + 1.0f);
        atomicAdd(&Amat[(size_t)c*NPC*NPC + (size_t)cc*NPC + r], dr*w*dc);
    }
    if (idx < NN) {
        int c = idx / NPC, n = idx % NPC;
        atomicAdd(&Amat[(size_t)c*NPC*NPC + (size_t)n*NPC + n], 1.0f/(deg[idx] + 1.0f));
    }
}

// ---------------- tiled f32 GEMM: out[c] = opt(A[c]@B[c] + bias[c]) ----------------
// BM=BN=64, BK=16, 256 threads, 4x4 per thread. Requires K%16==0, N2%64==0.
template<int M, int K, int N2, int BIAS, int RELU>
__global__ __launch_bounds__(256) void gemm_tiled(const float* __restrict__ A,
        const float* __restrict__ B, const float* __restrict__ bias,
        float* __restrict__ out) {
    __shared__ float As[16][68];   // [kk][row], pad 68 keeps conflicts <=2-way
    __shared__ float Bs[16][68];   // [kk][col]
    const int c  = blockIdx.z;
    const int m0 = blockIdx.x << 6, n0 = blockIdx.y << 6;
    const float* Ab = A + (size_t)c*M*K;
    const float* Bb = B + (size_t)c*K*N2;
    const int tid = threadIdx.x;
    const int tx = tid & 15, ty = tid >> 4;
    const int lrow = tid >> 2, lk4 = (tid & 3) << 2;     // A loader: 64 rows x 16 k
    const int lkb = tid >> 4, lcol4 = (tid & 15) << 2;   // B loader: 16 k x 64 cols
    float acc[4][4] = {};
    for (int k0 = 0; k0 < K; k0 += 16) {
        float4 a4 = make_float4(0.f, 0.f, 0.f, 0.f);
        int gr = m0 + lrow;
        if (gr < M) a4 = *(const float4*)(Ab + (size_t)gr*K + k0 + lk4);
        As[lk4+0][lrow] = a4.x; As[lk4+1][lrow] = a4.y;
        As[lk4+2][lrow] = a4.z; As[lk4+3][lrow] = a4.w;
        *(float4*)&Bs[lkb][lcol4] = *(const float4*)(Bb + (size_t)(k0+lkb)*N2 + n0 + lcol4);
        __syncthreads();
        #pragma unroll
        for (int kk = 0; kk < 16; ++kk) {
            float4 av = *(float4*)&As[kk][ty << 2];
            float4 bv = *(float4*)&Bs[kk][tx << 2];
            acc[0][0] += av.x*bv.x; acc[0][1] += av.x*bv.y; acc[0][2] += av.x*bv.z; acc[0][3] += av.x*bv.w;
            acc[1][0] += av.y*bv.x; acc[1][1] += av.y*bv.y; acc[1][2] += av.y*bv.z; acc[1][3] += av.y*bv.w;
            acc[2][0] += av.z*bv.x; acc[2][1] += av.z*bv.y; acc[2][2] += av.z*bv.z; acc[2][3] += av.z*bv.w;
            acc[3][0] += av.w*bv.x; acc[3][1] += av.w*bv.y; acc[3][2] += av.w*bv.z; acc[3][3] += av.w*bv.w;
        }
        __syncthreads();
    }
    #pragma unroll
    for (int i = 0; i < 4; ++i) {
        int gr = m0 + (ty << 2) + i;
        if (gr >= M) break;
        float4 o = make_float4(acc[i][0], acc[i][1], acc[i][2], acc[i][3]);
        if (BIAS) {
            const float* bb = bias + c*N2 + n0 + (tx << 2);
            o.x += bb[0]; o.y += bb[1]; o.z += bb[2]; o.w += bb[3];
        }
        if (RELU) {
            o.x = fmaxf(o.x, 0.f); o.y = fmaxf(o.y, 0.f);
            o.z = fmaxf(o.z, 0.f); o.w = fmaxf(o.w, 0.f);
        }
        *(float4*)(out + (size_t)c*M*N2 + (size_t)gr*N2 + n0 + (tx << 2)) = o;
    }
}

// ---------------- wprep: wa2 = W2@Wa, wb2 = W2@Wb, cab = b2·{Wa,Wb}  (1 block/cluster) ------
__global__ void wprep(const float* __restrict__ W2, const float* __restrict__ Watt,
                      const float* __restrict__ b2, float* __restrict__ wa2,
                      float* __restrict__ wb2, float* __restrict__ cab) {
    int c = blockIdx.x, k = threadIdx.x;   // 256 threads == HH
    const float* w2 = W2 + ((size_t)c*HH + k)*DOUT;
    float sa = 0.f, sb = 0.f;
    for (int d = 0; d < DOUT; ++d) { sa += w2[d]*Watt[d]; sb += w2[d]*Watt[DOUT+d]; }
    wa2[c*HH + k] = sa; wb2[c*HH + k] = sb;
    if (k < 2) {
        const float* bb = b2 + c*DOUT;
        const float* wv = Watt + k*DOUT;
        float s = 0.f;
        for (int d = 0; d < DOUT; ++d) s += bb[d]*wv[d];
        cab[k*C + c] = s;   // [0..4]=b2·Wa, [5..9]=b2·Wb
    }
}

// ---------------- tvec: ta[n] = h1[n]·wa2[c], tb[n] = h1[n]·wb2[c] (one wave per node) ------
__global__ void tvec(const float* __restrict__ h1, const float* __restrict__ wa2,
                     const float* __restrict__ wb2, float* __restrict__ ta,
                     float* __restrict__ tb) {
    int w = blockIdx.x*4 + (threadIdx.x >> 6);
    int lane = threadIdx.x & 63;
    if (w >= NN) return;
    int c = w / NPC;
    const float* hr = h1 + (size_t)w*HH;
    const float* wa = wa2 + c*HH;
    const float* wb = wb2 + c*HH;
    float sa = 0.f, sb = 0.f;
    for (int d = lane; d < HH; d += 64) { float h = hr[d]; sa += h*wa[d]; sb += h*wb[d]; }
    for (int off = 32; off; off >>= 1) { sa += __shfl_down(sa, off); sb += __shfl_down(sb, off); }
    if (!lane) { ta[w] = sa; tb[w] = sb; }
}

// ---------------- avbv: av[n] = A_row(n)·ta + b2·Wa   (one wave per node) ----------------
__global__ void avbv(const float* __restrict__ Amat, const float* __restrict__ ta,
                     const float* __restrict__ tb, const float* __restrict__ cab,
                     float* __restrict__ av, float* __restrict__ bv) {
    int w = blockIdx.x*4 + (threadIdx.x >> 6);
    int lane = threadIdx.x & 63;
    if (w >= NN) return;
    int c = w / NPC, n = w % NPC;
    const float* Ar = Amat + (size_t)c*NPC*NPC + (size_t)n*NPC;
    const float* tac = ta + c*NPC;
    const float* tbc = tb + c*NPC;
    float sa = 0.f, sb = 0.f;
    for (int m = lane; m < NPC; m += 64) { float a = Ar[m]; sa += a*tac[m]; sb += a*tbc[m]; }
    for (int off = 32; off; off >>= 1) { sa += __shfl_down(sa, off); sb += __shfl_down(sb, off); }
    if (!lane) { av[w] = sa + cab[c]; bv[w] = sb + cab[C + c]; }
}

// ---------------- stats: closed-form mean/std over all P pairs (double, shuffle-reduced) ----
__global__ void stats_kernel(const float* __restrict__ av, const float* __restrict__ bv,
                             const float* __restrict__ b_att, float* __restrict__ stats) {
    __shared__ double wred[5][4];
    __shared__ double wsum[4];
    int t = threadIdx.x;
    int lane = t & 63, wid = t >> 6;
    const int CH = 8;
    int lo = t*CH, hi = lo + CH; if (hi > NN) hi = NN; if (lo > NN) lo = NN;

    double sa1=0, sb1=0, sa2=0, sb2=0, csum=0;
    for (int i = lo; i < hi; ++i) {
        double a = av[i], b = bv[i];
        double wa = (double)(NN-1-i), wb = (double)i;
        sa1 += a*wa; sb1 += b*wb;
        sa2 += a*a*wa; sb2 += b*b*wb;
        csum += a;
    }
    // wave-level butterfly reductions (lane 0 holds wave total)
    double v0=sa1, v1=sb1, v2=sa2, v3=sb2;
    for (int off = 32; off; off >>= 1) {
        v0 += __shfl_down(v0, off); v1 += __shfl_down(v1, off);
        v2 += __shfl_down(v2, off); v3 += __shfl_down(v3, off);
    }
    if (!lane) { wred[0][wid]=v0; wred[1][wid]=v1; wred[2][wid]=v2; wred[3][wid]=v3; }
    // inclusive scan of per-thread csum within wave
    double x = csum;
    for (int off = 1; off < 64; off <<= 1) {
        double y = __shfl_up(x, off);
        if (lane >= off) x += y;
    }
    if (lane == 63) wsum[wid] = x;
    __syncthreads();
    double woff = 0;
    for (int wI = 0; wI < wid; ++wI) woff += wsum[wI];
    double run = woff + x - csum;   // exclusive prefix of a-sums before this chunk
    double ct = 0;
    for (int i = lo; i < hi; ++i) { ct += (double)bv[i]*run; run += (double)av[i]; }
    for (int off = 32; off; off >>= 1) ct += __shfl_down(ct, off);
    if (!lane) wred[4][wid] = ct;
    __syncthreads();
    if (t == 0) {
        double T0=0, T1=0, T2=0, T3=0, CT=0;
        for (int wI = 0; wI < 4; ++wI) {
            T0 += wred[0][wI]; T1 += wred[1][wI]; T2 += wred[2][wI];
            T3 += wred[3][wI]; CT += wred[4][wI];
        }
        double cc = (double)b_att[0];
        double P  = (double)NN*(double)(NN-1)/2.0;
        double S1 = T0 + T1 + cc*P;
        double S2 = T2 + T3 + 2.0*CT + 2.0*cc*S1 - cc*cc*P;
        double m  = S1/P;
        double var = (S2 - S1*S1/P)/(P - 1.0);
        stats[0] = (float)m;
        stats[1] = (float)sqrt(var);
    }
}

// ---------------- pair: all-pairs sigmoid output, one block per row i ----------------
__global__ void pair_kernel(const float* __restrict__ av, const float* __restrict__ bv,
                            const float* __restrict__ b_att, const float* __restrict__ stats,
                            float* __restrict__ out) {
    int i = blockIdx.x;
    long off = (long)i*(NN-1) - ((long)i*(i-1))/2;
    float m = stats[0], s = stats[1];
    float inv = 1.0f/s;
    float ai = av[i] + b_att[0] - m;
    for (int j = i + 1 + threadIdx.x; j < NN; j += blockDim.x) {
        float z = (ai + bv[j]) * inv;
        out[off + (j - i - 1)] = 1.0f/(1.0f + __expf(-z));
    }
}

extern "C" void kernel_launch(void* const* d_in, const int* in_sizes, int n_in,
                              void* d_out, int out_size, void* d_ws, size_t ws_size,
                              hipStream_t stream) {
    const float* x    = (const float*)d_in[0];
    const float* ew   = (const float*)d_in[1];
    const float* W1   = (const float*)d_in[2];
    const float* b1   = (const float*)d_in[3];
    const float* W2   = (const float*)d_in[4];
    const float* b2   = (const float*)d_in[5];
    const float* Watt = (const float*)d_in[6];
    const float* batt = (const float*)d_in[7];
    const int*   ei   = (const int*)d_in[8];
    float* out = (float*)d_out;
    float* ws  = (float*)d_ws;

    // workspace layout (floats)
    float* Amat  = ws;                  // 800000
    float* deg   = Amat + 800000;       // 2000   (memset together with Amat)
    float* xW    = deg  + 2000;         // 512000
    float* h1    = xW   + 512000;       // 512000
    float* wa2   = h1   + 512000;       // 1280
    float* wb2   = wa2  + 1280;         // 1280
    float* cab   = wb2  + 1280;         // 10 (+2 pad)
    float* ta    = cab  + 12;           // 2000
    float* tb    = ta   + 2000;         // 2000
    float* av    = tb   + 2000;         // 2000
    float* bv    = av   + 2000;         // 2000
    float* stats = bv   + 2000;         // 2

    hipMemsetAsync(Amat, 0, (size_t)(800000 + 2000)*sizeof(float), stream);

    deg_kernel<<<(NE + 255)/256, 256, 0, stream>>>(ew, ei, deg);
    adj_kernel<<<(NE + 255)/256, 256, 0, stream>>>(ew, ei, deg, Amat);

    // layer 1: xW = x@W1 ; h1 = relu(A@xW + b1)
    gemm_tiled<NPC, DF,  HH, 0, 0><<<dim3(7, 4, C), 256, 0, stream>>>(x,    W1, nullptr, xW);
    gemm_tiled<NPC, NPC, HH, 1, 1><<<dim3(7, 4, C), 256, 0, stream>>>(Amat, xW, b1,      h1);

    // layer 2 collapsed: av = A@(h1@(W2·Wa)) + b2·Wa  (same for b)
    wprep<<<C, 256, 0, stream>>>(W2, Watt, b2, wa2, wb2, cab);
    tvec<<<(NN + 3)/4, 256, 0, stream>>>(h1, wa2, wb2, ta, tb);
    avbv<<<(NN + 3)/4, 256, 0, stream>>>(Amat, ta, tb, cab, av, bv);

    stats_kernel<<<1, 256, 0, stream>>>(av, bv, batt, stats);
    pair_kernel<<<NN, 256, 0, stream>>>(av, bv, batt, stats, out);
}

// Round 5
// 128.803 us; speedup vs baseline: 3.4631x; 1.0949x over previous
//
#include <hip/hip_runtime.h>
#include <math.h>

#define C    5
#define NPC  400
#define DF   64
#define HH   256
#define DOUT 64
#define EPC  12800
#define NN   (C*NPC)   // 2000
#define NE   (C*EPC)   // 64000

// ---------------- K1: edge-weight degree scatter ----------------
__global__ void deg_kernel(const float* __restrict__ ew, const int* __restrict__ ei,
                           float* __restrict__ deg) {
    int idx = blockIdx.x*256 + threadIdx.x;
    if (idx >= NE) return;
    int c = idx / EPC, e = idx % EPC;
    int col = ei[(size_t)c*2*EPC + EPC + e];
    atomicAdd(&deg[c*NPC + col], ew[(size_t)c*EPC + e]);
}

// ---------------- K2: adjacency scatter + fused wprep (independent wave jobs) ----------------
// A[c][col][row] = dis[row]*w*dis[col], dis = rsqrt(deg+1); diag += 1/(deg+1)
// wprep: wa2[c,k] = W2[c,k,:]·Wa, wb2 = ·Wb; cab[which*C+c] = b2[c]·W{a,b}
__global__ void adj_wprep_kernel(const float* __restrict__ ew, const int* __restrict__ ei,
                                 const float* __restrict__ deg, const float* __restrict__ W2,
                                 const float* __restrict__ Watt, const float* __restrict__ b2,
                                 float* __restrict__ Amat, float* __restrict__ wa2,
                                 float* __restrict__ wb2, float* __restrict__ cab) {
    int idx = blockIdx.x*256 + threadIdx.x;
    if (idx < NE) {
        int c = idx / EPC, e = idx % EPC;
        const int* row = ei + (size_t)c*2*EPC;
        int r  = row[e];
        int cc = row[EPC + e];
        float w  = ew[(size_t)c*EPC + e];
        float dr = rsqrtf(deg[c*NPC + r]  + 1.0f);
        float dc = rsqrtf(deg[c*NPC + cc] + 1.0f);
        atomicAdd(&Amat[(size_t)c*NPC*NPC + (size_t)cc*NPC + r], dr*w*dc);
    }
    if (idx < NN) {
        int c = idx / NPC, n = idx % NPC;
        atomicAdd(&Amat[(size_t)c*NPC*NPC + (size_t)n*NPC + n], 1.0f/(deg[idx] + 1.0f));
    }
    // wave jobs: 1280 wa2/wb2 rows + 10 cab dots
    int W = blockIdx.x*4 + (threadIdx.x >> 6);
    int lane = threadIdx.x & 63;
    if (W < C*HH) {
        int c = W / HH, k = W % HH;
        float v  = W2[((size_t)c*HH + k)*DOUT + lane];
        float sa = v*Watt[lane];
        float sb = v*Watt[DOUT + lane];
        for (int off = 32; off; off >>= 1) { sa += __shfl_down(sa, off); sb += __shfl_down(sb, off); }
        if (!lane) { wa2[W] = sa; wb2[W] = sb; }
    } else if (W < C*HH + 2*C) {
        int j = W - C*HH;
        int which = j / C, c = j % C;
        float s = b2[c*DOUT + lane]*Watt[which*DOUT + lane];
        for (int off = 32; off; off >>= 1) s += __shfl_down(s, off);
        if (!lane) cab[which*C + c] = s;
    }
}

// ---------------- tiled f32 GEMM, BM=32 BN=64 BK=16, 256 thr, 2x4/thread ----------------
// FUSETAB: skip dense store; accumulate ta/tb = rowsum(relu(acc+bias) * wa2/wb2) via atomics.
template<int M, int K, int N2, int BIAS, int RELU, int FUSETAB>
__global__ __launch_bounds__(256) void gemm32(const float* __restrict__ A,
        const float* __restrict__ B, const float* __restrict__ bias,
        float* __restrict__ out, const float* __restrict__ wa2,
        const float* __restrict__ wb2, float* __restrict__ ta, float* __restrict__ tb) {
    __shared__ float As[16][34];   // [kk][row]
    __shared__ float Bs[16][68];   // [kk][col]
    const int c  = blockIdx.z;
    const int m0 = blockIdx.x << 5, n0 = blockIdx.y << 6;
    const float* Ab = A + (size_t)c*M*K;
    const float* Bb = B + (size_t)c*K*N2;
    const int tid = threadIdx.x;
    const int tx = tid & 15, ty = tid >> 4;
    const int lrowA = tid >> 3, lk2 = (tid & 7) << 1;     // A loader: 32 rows x 16 k (float2)
    const int lkb = tid >> 4, lcol4 = (tid & 15) << 2;    // B loader: 16 k x 64 cols (float4)
    float acc[2][4] = {};
    for (int k0 = 0; k0 < K; k0 += 16) {
        float2 a2 = make_float2(0.f, 0.f);
        int gr = m0 + lrowA;
        if (gr < M) a2 = *(const float2*)(Ab + (size_t)gr*K + k0 + lk2);
        As[lk2][lrowA] = a2.x; As[lk2+1][lrowA] = a2.y;
        *(float4*)&Bs[lkb][lcol4] = *(const float4*)(Bb + (size_t)(k0+lkb)*N2 + n0 + lcol4);
        __syncthreads();
        #pragma unroll
        for (int kk = 0; kk < 16; ++kk) {
            float2 av = *(float2*)&As[kk][ty << 1];
            float4 bv = *(float4*)&Bs[kk][tx << 2];
            acc[0][0] += av.x*bv.x; acc[0][1] += av.x*bv.y; acc[0][2] += av.x*bv.z; acc[0][3] += av.x*bv.w;
            acc[1][0] += av.y*bv.x; acc[1][1] += av.y*bv.y; acc[1][2] += av.y*bv.z; acc[1][3] += av.y*bv.w;
        }
        __syncthreads();
    }
    if (FUSETAB) {
        float pa0 = 0.f, pa1 = 0.f, pb0 = 0.f, pb1 = 0.f;
        #pragma unroll
        for (int j = 0; j < 4; ++j) {
            int col = n0 + (tx << 2) + j;
            float bj  = bias[c*N2 + col];
            float waj = wa2[c*N2 + col];
            float wbj = wb2[c*N2 + col];
            float o0 = fmaxf(acc[0][j] + bj, 0.f);
            float o1 = fmaxf(acc[1][j] + bj, 0.f);
            pa0 += o0*waj; pa1 += o1*waj;
            pb0 += o0*wbj; pb1 += o1*wbj;
        }
        #pragma unroll
        for (int off = 1; off < 16; off <<= 1) {
            pa0 += __shfl_xor(pa0, off); pa1 += __shfl_xor(pa1, off);
            pb0 += __shfl_xor(pb0, off); pb1 += __shfl_xor(pb1, off);
        }
        if (tx == 0) {
            int gr0 = m0 + (ty << 1);
            if (gr0 < M)     { atomicAdd(&ta[c*M + gr0],     pa0); atomicAdd(&tb[c*M + gr0],     pb0); }
            if (gr0 + 1 < M) { atomicAdd(&ta[c*M + gr0 + 1], pa1); atomicAdd(&tb[c*M + gr0 + 1], pb1); }
        }
    } else {
        #pragma unroll
        for (int i = 0; i < 2; ++i) {
            int gr = m0 + (ty << 1) + i;
            if (gr >= M) break;
            float4 o = make_float4(acc[i][0], acc[i][1], acc[i][2], acc[i][3]);
            if (BIAS) {
                const float* bb = bias + c*N2 + n0 + (tx << 2);
                o.x += bb[0]; o.y += bb[1]; o.z += bb[2]; o.w += bb[3];
            }
            if (RELU) {
                o.x = fmaxf(o.x, 0.f); o.y = fmaxf(o.y, 0.f);
                o.z = fmaxf(o.z, 0.f); o.w = fmaxf(o.w, 0.f);
            }
            *(float4*)(out + (size_t)c*M*N2 + (size_t)gr*N2 + n0 + (tx << 2)) = o;
        }
    }
}

// ---------------- avbv: av[n] = A_row(n)·ta + b2·Wa   (one wave per node) ----------------
__global__ void avbv(const float* __restrict__ Amat, const float* __restrict__ ta,
                     const float* __restrict__ tb, const float* __restrict__ cab,
                     float* __restrict__ av, float* __restrict__ bv) {
    int w = blockIdx.x*4 + (threadIdx.x >> 6);
    int lane = threadIdx.x & 63;
    if (w >= NN) return;
    int c = w / NPC, n = w % NPC;
    const float* Ar = Amat + (size_t)c*NPC*NPC + (size_t)n*NPC;
    const float* tac = ta + c*NPC;
    const float* tbc = tb + c*NPC;
    float sa = 0.f, sb = 0.f;
    for (int m = lane; m < NPC; m += 64) { float a = Ar[m]; sa += a*tac[m]; sb += a*tbc[m]; }
    for (int off = 32; off; off >>= 1) { sa += __shfl_down(sa, off); sb += __shfl_down(sb, off); }
    if (!lane) { av[w] = sa + cab[c]; bv[w] = sb + cab[C + c]; }
}

// ---------------- stats: closed-form mean/std over all P pairs (double, shuffle-reduced) ----
__global__ void stats_kernel(const float* __restrict__ av, const float* __restrict__ bv,
                             const float* __restrict__ b_att, float* __restrict__ stats) {
    __shared__ double wred[5][4];
    __shared__ double wsum[4];
    int t = threadIdx.x;
    int lane = t & 63, wid = t >> 6;
    const int CH = 8;
    int lo = t*CH, hi = lo + CH; if (hi > NN) hi = NN; if (lo > NN) lo = NN;

    double sa1=0, sb1=0, sa2=0, sb2=0, csum=0;
    for (int i = lo; i < hi; ++i) {
        double a = av[i], b = bv[i];
        double wa = (double)(NN-1-i), wb = (double)i;
        sa1 += a*wa; sb1 += b*wb;
        sa2 += a*a*wa; sb2 += b*b*wb;
        csum += a;
    }
    double v0=sa1, v1=sb1, v2=sa2, v3=sb2;
    for (int off = 32; off; off >>= 1) {
        v0 += __shfl_down(v0, off); v1 += __shfl_down(v1, off);
        v2 += __shfl_down(v2, off); v3 += __shfl_down(v3, off);
    }
    if (!lane) { wred[0][wid]=v0; wred[1][wid]=v1; wred[2][wid]=v2; wred[3][wid]=v3; }
    double x = csum;
    for (int off = 1; off < 64; off <<= 1) {
        double y = __shfl_up(x, off);
        if (lane >= off) x += y;
    }
    if (lane == 63) wsum[wid] = x;
    __syncthreads();
    double woff = 0;
    for (int wI = 0; wI < wid; ++wI) woff += wsum[wI];
    double run = woff + x - csum;
    double ct = 0;
    for (int i = lo; i < hi; ++i) { ct += (double)bv[i]*run; run += (double)av[i]; }
    for (int off = 32; off; off >>= 1) ct += __shfl_down(ct, off);
    if (!lane) wred[4][wid] = ct;
    __syncthreads();
    if (t == 0) {
        double T0=0, T1=0, T2=0, T3=0, CT=0;
        for (int wI = 0; wI < 4; ++wI) {
            T0 += wred[0][wI]; T1 += wred[1][wI]; T2 += wred[2][wI];
            T3 += wred[3][wI]; CT += wred[4][wI];
        }
        double cc = (double)b_att[0];
        double P  = (double)NN*(double)(NN-1)/2.0;
        double S1 = T0 + T1 + cc*P;
        double S2 = T2 + T3 + 2.0*CT + 2.0*cc*S1 - cc*cc*P;
        double m  = S1/P;
        double var = (S2 - S1*S1/P)/(P - 1.0);
        stats[0] = (float)m;
        stats[1] = (float)sqrt(var);
    }
}

// ---------------- pair: all-pairs sigmoid output, one block per row i ----------------
__global__ void pair_kernel(const float* __restrict__ av, const float* __restrict__ bv,
                            const float* __restrict__ b_att, const float* __restrict__ stats,
                            float* __restrict__ out) {
    int i = blockIdx.x;
    long off = (long)i*(NN-1) - ((long)i*(i-1))/2;
    float m = stats[0], s = stats[1];
    float inv = 1.0f/s;
    float ai = av[i] + b_att[0] - m;
    for (int j = i + 1 + threadIdx.x; j < NN; j += blockDim.x) {
        float z = (ai + bv[j]) * inv;
        out[off + (j - i - 1)] = 1.0f/(1.0f + __expf(-z));
    }
}

extern "C" void kernel_launch(void* const* d_in, const int* in_sizes, int n_in,
                              void* d_out, int out_size, void* d_ws, size_t ws_size,
                              hipStream_t stream) {
    const float* x    = (const float*)d_in[0];
    const float* ew   = (const float*)d_in[1];
    const float* W1   = (const float*)d_in[2];
    const float* b1   = (const float*)d_in[3];
    const float* W2   = (const float*)d_in[4];
    const float* b2   = (const float*)d_in[5];
    const float* Watt = (const float*)d_in[6];
    const float* batt = (const float*)d_in[7];
    const int*   ei   = (const int*)d_in[8];
    float* out = (float*)d_out;
    float* ws  = (float*)d_ws;

    // workspace layout (floats) — first 806000 are zeroed in one fill
    float* Amat  = ws;                  // 800000
    float* deg   = Amat + 800000;       // 2000
    float* ta    = deg  + 2000;         // 2000
    float* tb    = ta   + 2000;         // 2000
    float* xW    = tb   + 2000;         // 512000
    float* wa2   = xW   + 512000;       // 1280
    float* wb2   = wa2  + 1280;         // 1280
    float* cab   = wb2  + 1280;         // 10 (+2 pad)
    float* av    = cab  + 12;           // 2000
    float* bv    = av   + 2000;         // 2000
    float* stats = bv   + 2000;         // 2

    hipMemsetAsync(ws, 0, (size_t)806000*sizeof(float), stream);

    deg_kernel<<<(NE + 255)/256, 256, 0, stream>>>(ew, ei, deg);
    adj_wprep_kernel<<<323, 256, 0, stream>>>(ew, ei, deg, W2, Watt, b2, Amat, wa2, wb2, cab);

    // layer 1: xW = x@W1 ; then fused: relu(A@xW+b1)·{wa2,wb2} -> ta,tb (no h1 materialized)
    gemm32<NPC, DF,  HH, 0, 0, 0><<<dim3(13, 4, C), 256, 0, stream>>>(x,    W1, nullptr, xW,
                                                                      nullptr, nullptr, nullptr, nullptr);
    gemm32<NPC, NPC, HH, 1, 1, 1><<<dim3(13, 4, C), 256, 0, stream>>>(Amat, xW, b1, nullptr,
                                                                      wa2, wb2, ta, tb);

    avbv<<<(NN + 3)/4, 256, 0, stream>>>(Amat, ta, tb, cab, av, bv);
    stats_kernel<<<1, 256, 0, stream>>>(av, bv, batt, stats);
    pair_kernel<<<NN, 256, 0, stream>>>(av, bv, batt, stats, out);
}